// Round 4
// baseline (174.990 us; speedup 1.0000x reference)
//
#include <hip/hip_runtime.h>

#define TT 1024
#define SS 128
#define FF 8
#define CC 256
#define BH 8
#define CHUNK_T 4
#define NCHUNK (TT / CHUNK_T)   // 256 chunks per batch

__global__ __launch_bounds__(256) void zero_out(float4* __restrict__ out) {
    out[blockIdx.x * 256 + threadIdx.x] = make_float4(0.f, 0.f, 0.f, 0.f);
}

// Uniform-work blocks: each block = (chunk of CHUNK_T t-rows) x (batch b).
// Thread tid = channel. Per-segment register accumulation, atomic flush.
__global__ __launch_bounds__(256) void agg_atomic(const float* __restrict__ e,
                                                  const int* __restrict__ dsrc,
                                                  float* __restrict__ out) {
    int chunk = blockIdx.x;   // 0..NCHUNK-1
    int b     = blockIdx.y;   // 0..BH-1
    int tid   = threadIdx.x;  // channel 0..255

    // --- inclusive scan of d[b, :] into LDS ---
    __shared__ int cumbuf[SS];
    if (tid < SS) cumbuf[tid] = dsrc[b * SS + tid];
    __syncthreads();
    #pragma unroll
    for (int off = 1; off < SS; off <<= 1) {
        int v = 0;
        if (tid < SS && tid >= off) v = cumbuf[tid - off];
        __syncthreads();
        if (tid < SS) cumbuf[tid] += v;
        __syncthreads();
    }

    int t0 = chunk * CHUNK_T;
    const float* ep = e + ((size_t)b * TT + t0) * (FF * CC) + tid;

    float acc = 0.f;
    int cur_seg = -1;

    #pragma unroll
    for (int i = 0; i < CHUNK_T; i++) {
        int t = t0 + i;
        // seg = searchsorted(cum, t, side='right') = first idx with cum[idx] > t
        int lo = 0, hi = SS;
        while (lo < hi) {
            int mid = (lo + hi) >> 1;
            if (cumbuf[mid] <= t) lo = mid + 1; else hi = mid;
        }
        int seg = lo;   // block-uniform

        if (seg != cur_seg) {
            if (cur_seg >= 0 && cur_seg < SS) {
                int dlo = (cur_seg == 0) ? 0 : cumbuf[cur_seg - 1];
                int dc  = cumbuf[cur_seg] - dlo;              // > 0: segment had rows
                float inv = 1.0f / (float)(dc * FF);
                atomicAdd(&out[((size_t)b * SS + cur_seg) * CC + tid], acc * inv);
            }
            acc = 0.f;
            cur_seg = seg;
        }
        if (seg < SS) {
            float v = 0.f;
            #pragma unroll
            for (int f = 0; f < FF; f++) v += ep[(size_t)(i * FF + f) * CC];
            acc += v;
        }
    }
    if (cur_seg >= 0 && cur_seg < SS) {
        int dlo = (cur_seg == 0) ? 0 : cumbuf[cur_seg - 1];
        int dc  = cumbuf[cur_seg] - dlo;
        float inv = 1.0f / (float)(dc * FF);
        atomicAdd(&out[((size_t)b * SS + cur_seg) * CC + tid], acc * inv);
    }
}

extern "C" void kernel_launch(void* const* d_in, const int* in_sizes, int n_in,
                              void* d_out, int out_size, void* d_ws, size_t ws_size,
                              hipStream_t stream) {
    const float* e   = (const float*)d_in[0];
    const int*   d   = (const int*)d_in[1];
    float*       out = (float*)d_out;

    // out = BH*SS*CC = 262144 floats = 65536 float4 -> 256 blocks x 256 threads
    zero_out<<<256, 256, 0, stream>>>((float4*)out);
    agg_atomic<<<dim3(NCHUNK, BH), 256, 0, stream>>>(e, d, out);
}